// Round 6
// baseline (58.346 us; speedup 1.0000x reference)
//
#include <hip/hip_runtime.h>
#include <math.h>

#define SCALE 8
#define PSZ 32

// ---- constant twiddles: W_32^k = cos(2pi k/32) - i sin(2pi k/32), k=0..15 ----
__device__ constexpr float C32[16] = {
     1.000000000000000f,  0.980785280403230f,  0.923879532511287f,  0.831469612302545f,
     0.707106781186548f,  0.555570233019602f,  0.382683432365090f,  0.195090322016128f,
     0.000000000000000f, -0.195090322016128f, -0.382683432365090f, -0.555570233019602f,
    -0.707106781186548f, -0.831469612302545f, -0.923879532511287f, -0.980785280403230f };
__device__ constexpr float S32[16] = {
     0.000000000000000f,  0.195090322016128f,  0.382683432365090f,  0.555570233019602f,
     0.707106781186548f,  0.831469612302545f,  0.923879532511287f,  0.980785280403230f,
     1.000000000000000f,  0.980785280403230f,  0.923879532511287f,  0.831469612302545f,
     0.707106781186548f,  0.555570233019602f,  0.382683432365090f,  0.195090322016128f };

__device__ __forceinline__ constexpr int brev5(int i) {
    return ((i & 1) << 4) | ((i & 2) << 2) | (i & 4) | ((i & 8) >> 2) | ((i & 16) >> 4);
}

// in-place 32-point radix-2 DIT FFT, fully unrolled (all indices compile-time)
__device__ __forceinline__ void fft32(float re[PSZ], float im[PSZ]) {
#pragma unroll
    for (int i = 0; i < 32; ++i) {
        const int j = brev5(i);
        if (j > i) {
            float t = re[i]; re[i] = re[j]; re[j] = t;
            t = im[i]; im[i] = im[j]; im[j] = t;
        }
    }
#pragma unroll
    for (int s = 1; s <= 5; ++s) {
        const int m = 1 << s;
        const int h = m >> 1;
        const int tstep = 32 >> s;
#pragma unroll
        for (int k = 0; k < 32; k += m) {
#pragma unroll
            for (int j = 0; j < h; ++j) {
                const float wr = C32[j * tstep];
                const float wi = -S32[j * tstep];
                const int a = k + j;
                const int b = k + j + h;
                const float tr = wr * re[b] - wi * im[b];
                const float ti = wr * im[b] + wi * re[b];
                re[b] = re[a] - tr; im[b] = im[a] - ti;
                re[a] = re[a] + tr; im[a] = im[a] + ti;
            }
        }
    }
}

// bf16x2 pack/unpack (round-half-up via +0x8000)
__device__ __forceinline__ unsigned pack_bf2(float hi, float lo) {
    const unsigned uh = __float_as_uint(hi) + 0x8000u;
    const unsigned ul = __float_as_uint(lo) + 0x8000u;
    return (uh & 0xFFFF0000u) | (ul >> 16);
}
__device__ __forceinline__ float bf_hi(unsigned u) { return __uint_as_float(u & 0xFFFF0000u); }
__device__ __forceinline__ float bf_lo(unsigned u) { return __uint_as_float(u << 16); }

// ---- gray precompute: g = w0*R + w1*G + w2*B, vectorized float4 ----
__global__ __launch_bounds__(256) void gray_kernel(
        const float* __restrict__ x, const float* __restrict__ w,
        float* __restrict__ g, int n4, long long HW) {
    const int i = blockIdx.x * 256 + threadIdx.x;
    if (i >= n4) return;
    const float w0 = w[0], w1 = w[1], w2 = w[2];
    const float4 a = reinterpret_cast<const float4*>(x)[i];
    const float4 b = reinterpret_cast<const float4*>(x + HW)[i];
    const float4 c = reinterpret_cast<const float4*>(x + 2 * HW)[i];
    float4 o;
    o.x = w0 * a.x + w1 * b.x + w2 * c.x;
    o.y = w0 * a.y + w1 * b.y + w2 * c.y;
    o.z = w0 * a.z + w1 * b.z + w2 * c.z;
    o.w = w0 * a.w + w1 * b.w + w2 * c.w;
    reinterpret_cast<float4*>(g)[i] = o;
}

// ---- row-spectrum precompute ----
// Each distinct (image row y, column window c) row-FFT is shared by up to 4
// patches vertically — compute it ONCE. Thread t handles windows (c0, c0+1)
// of row y packed as a + i*b into one complex FFT32 (windows are 8px apart,
// union = 40px). Output: Hermitian half k=0..16 as bf16x2; slot 0 packs the
// two real bins (F(0), F(16)). Layout spec[(y*mat_w + c)*16 + k] -> per
// thread 32 consecutive u32 = 8 fully-coalesced uint4 stores.
__global__ __launch_bounds__(256, 4) void rowfft_kernel(
        const float* __restrict__ g, unsigned* __restrict__ spec,
        int H, int W, int mat_w) {
    const int cpairs = mat_w >> 1;          // mat_w even (host-enforced)
    const int t = blockIdx.x * 256 + threadIdx.x;
    if (t >= H * cpairs) return;
    const int y = t / cpairs, cp = t - y * cpairs;
    const int c0 = 2 * cp;

    const float4* g4 = reinterpret_cast<const float4*>(g + (size_t)y * W + (size_t)c0 * SCALE);
    float win[40];
#pragma unroll
    for (int q = 0; q < 10; ++q) {
        const float4 v = g4[q];
        win[4 * q + 0] = v.x; win[4 * q + 1] = v.y;
        win[4 * q + 2] = v.z; win[4 * q + 3] = v.w;
    }
    float re[PSZ], im[PSZ];
#pragma unroll
    for (int i = 0; i < PSZ; ++i) { re[i] = win[i]; im[i] = win[i + 8]; }

    fft32(re, im);   // FFT of window c0 + i * window c0+1

    unsigned outA[16], outB[16];
    outA[0] = pack_bf2(re[0], re[16]);      // F_A(0), F_A(16) both real
    outB[0] = pack_bf2(im[0], im[16]);      // F_B(0), F_B(16)
#pragma unroll
    for (int k = 1; k <= 15; ++k) {
        const int m = 32 - k;
        const float far_ = 0.5f * (re[k] + re[m]);
        const float fai_ = 0.5f * (im[k] - im[m]);
        const float fbr_ = 0.5f * (im[k] + im[m]);
        const float fbi_ = 0.5f * (re[m] - re[k]);
        outA[k] = pack_bf2(far_, fai_);
        outB[k] = pack_bf2(fbr_, fbi_);
    }
    uint4* s4 = reinterpret_cast<uint4*>(spec + ((size_t)y * mat_w + c0) * 16);
#pragma unroll
    for (int q = 0; q < 4; ++q)
        s4[q] = make_uint4(outA[4 * q], outA[4 * q + 1], outA[4 * q + 2], outA[4 * q + 3]);
#pragma unroll
    for (int q = 0; q < 4; ++q)
        s4[4 + q] = make_uint4(outB[4 * q], outB[4 * q + 1], outB[4 * q + 2], outB[4 * q + 3]);
}

// ---- column FFT + masked log-power (no LDS, no barrier) ----
// 128-thread block = 8 patches. Lane (pl=lane>>4, slot=lane&15): reads its
// column's 32 row-spectrum entries (16 lanes of a group read 16 consecutive
// u32 = 64B; 4 groups = 4 consecutive windows), FFT32, Hermitian-mirror
// masked log-power, 16-lane shuffle reduce.
__global__ __launch_bounds__(128, 4) void colfft_kernel(
        const unsigned* __restrict__ spec, float* __restrict__ out,
        int mat_h, int mat_w) {
    const int tid = threadIdx.x;
    const int wid = tid >> 6, lane = tid & 63;
    const int pl = lane >> 4, slot = lane & 15;
    const int total = mat_h * mat_w;
    int p = blockIdx.x * 8 + wid * 4 + pl;
    if (p > total - 1) p = total - 1;     // duplicates write identical values
    const int ph = p / mat_w, pw = p - ph * mat_w;

    const unsigned* sp = spec + ((size_t)(ph * SCALE) * mat_w + pw) * 16 + slot;
    const size_t rstride = (size_t)mat_w * 16;

    float cre[PSZ], cim[PSZ];
#pragma unroll
    for (int r2 = 0; r2 < PSZ; ++r2) {
        const unsigned u = sp[r2 * rstride];
        cre[r2] = bf_hi(u);
        cim[r2] = bf_lo(u);
    }

    fft32(cre, cim);

    float s0 = 0.0f, s1 = 0.0f;
    if (slot == 0) {
        // packed pair (col 0, col 16): unpack kr=0..16, Hermitian-in-kr weights
#pragma unroll
        for (int kr = 0; kr <= 16; ++kr) {
            const int m = (32 - kr) & 31;
            const float g0r = 0.5f * (cre[kr] + cre[m]);
            const float g0i = 0.5f * (cim[kr] - cim[m]);
            const float g1r = 0.5f * (cim[kr] + cim[m]);
            const float g1i = 0.5f * (cre[m] - cre[kr]);
            const float w0c = (kr >= 7 ? 1.0f : 0.0f) + ((kr >= 8 && kr <= 15) ? 1.0f : 0.0f);
            const float w16c = 1.0f + ((kr >= 1 && kr <= 15) ? 1.0f : 0.0f);
            if (w0c > 0.0f)
                s0 = fmaf(w0c, __logf(g0r * g0r + g0i * g0i + 1.0f), s0);
            s1 = fmaf(w16c, __logf(g1r * g1r + g1i * g1i + 1.0f), s1);
        }
    } else {
        const float b1f = (slot >= 7) ? 1.0f : 0.0f;
        const float m1f = (slot >= 8) ? 1.0f : 0.0f;
#pragma unroll
        for (int kr = 0; kr < 32; ++kr) {
            const float lp = __logf(cre[kr] * cre[kr] + cim[kr] * cim[kr] + 1.0f);
            float wgt;
            if (kr >= 8 && kr <= 24)      wgt = 2.0f;
            else if (kr == 7)             wgt = 1.0f + m1f;
            else if (kr == 25)            wgt = b1f + 1.0f;
            else                          wgt = b1f + m1f;
            if (kr & 1) s1 = fmaf(wgt, lp, s1);
            else        s0 = fmaf(wgt, lp, s0);
        }
    }
    float s = s0 + s1;

#pragma unroll
    for (int off = 8; off >= 1; off >>= 1) s += __shfl_xor(s, off, 16);
    if (slot == 0) out[p] = s;
}

// ---- fallback: R5 fused patch kernel (odd shapes / small workspace) ----
template <bool GRAY_PRE>
__global__ __launch_bounds__(128) void hfdft_patch_kernel(
        const float* __restrict__ x, const float* __restrict__ w,
        float* __restrict__ out, int H, int W, int mat_h, int mat_w) {
    __shared__ unsigned cb[8 * 528];

    const int tid = threadIdx.x;
    const int wid = tid >> 6;
    const int lane = tid & 63;
    const int P0 = blockIdx.x * 8 + wid * 4;
    const int total = mat_h * mat_w;
    const long long HW = (long long)H * W;
    unsigned* cbw = cb + wid * 4 * 528;

    {
        const int g = lane >> 5, r = lane & 31;
        int pA = P0 + 2 * g;
        if (pA > total - 1) pA = total - 1;
        int pB = pA + 1; if (pB > total - 1) pB = total - 1;
        const int phA = pA / mat_w, pwA = pA % mat_w;
        const int phB = pB / mat_w, pwB = pB % mat_w;
        const bool adj = (phA == phB) && (pwB == pwA + 1);

        float re[PSZ], im[PSZ];
        if (GRAY_PRE) {
            if (adj) {
                const int base = (phA * SCALE + r) * W + pwA * SCALE;
                const float4* g4 = reinterpret_cast<const float4*>(x + base);
                float win[40];
#pragma unroll
                for (int q = 0; q < 10; ++q) {
                    const float4 v = g4[q];
                    win[4 * q + 0] = v.x; win[4 * q + 1] = v.y;
                    win[4 * q + 2] = v.z; win[4 * q + 3] = v.w;
                }
#pragma unroll
                for (int i = 0; i < PSZ; ++i) { re[i] = win[i]; im[i] = win[i + 8]; }
            } else {
                const int baseA = (phA * SCALE + r) * W + pwA * SCALE;
                const int baseB = (phB * SCALE + r) * W + pwB * SCALE;
#pragma unroll
                for (int i = 0; i < PSZ; ++i) { re[i] = x[baseA + i]; im[i] = x[baseB + i]; }
            }
        } else {
            const float w0 = w[0], w1 = w[1], w2 = w[2];
            const int baseA = (phA * SCALE + r) * W + pwA * SCALE;
            const int baseB = (phB * SCALE + r) * W + pwB * SCALE;
#pragma unroll
            for (int i = 0; i < PSZ; ++i) {
                re[i] = w0 * x[baseA + i] + w1 * x[HW + baseA + i] + w2 * x[2 * HW + baseA + i];
                im[i] = w0 * x[baseB + i] + w1 * x[HW + baseB + i] + w2 * x[2 * HW + baseB + i];
            }
        }

        fft32(re, im);

        unsigned* cbA = cbw + (2 * g) * 528;
        unsigned* cbB = cbA + 528;
        cbA[r] = pack_bf2(re[0], re[16]);
        cbB[r] = pack_bf2(im[0], im[16]);
#pragma unroll
        for (int k = 1; k <= 15; ++k) {
            const int m = 32 - k;
            const float far_ = 0.5f * (re[k] + re[m]);
            const float fai_ = 0.5f * (im[k] - im[m]);
            const float fbr_ = 0.5f * (im[k] + im[m]);
            const float fbi_ = 0.5f * (re[m] - re[k]);
            cbA[k * 33 + r] = pack_bf2(far_, fai_);
            cbB[k * 33 + r] = pack_bf2(fbr_, fbi_);
        }
    }

    asm volatile("s_waitcnt lgkmcnt(0)" ::: "memory");

    {
        const int pl = lane >> 4, slot = lane & 15;
        const int p = P0 + pl;
        const unsigned* cbp = cbw + pl * 528 + slot * 33;

        float cre[PSZ], cim[PSZ];
#pragma unroll
        for (int r2 = 0; r2 < PSZ; ++r2) {
            const unsigned u = cbp[r2];
            cre[r2] = bf_hi(u);
            cim[r2] = bf_lo(u);
        }

        fft32(cre, cim);

        float s0 = 0.0f, s1 = 0.0f;
        if (slot == 0) {
#pragma unroll
            for (int kr = 0; kr <= 16; ++kr) {
                const int m = (32 - kr) & 31;
                const float g0r = 0.5f * (cre[kr] + cre[m]);
                const float g0i = 0.5f * (cim[kr] - cim[m]);
                const float g1r = 0.5f * (cim[kr] + cim[m]);
                const float g1i = 0.5f * (cre[m] - cre[kr]);
                const float w0c = (kr >= 7 ? 1.0f : 0.0f) + ((kr >= 8 && kr <= 15) ? 1.0f : 0.0f);
                const float w16c = 1.0f + ((kr >= 1 && kr <= 15) ? 1.0f : 0.0f);
                if (w0c > 0.0f)
                    s0 = fmaf(w0c, __logf(g0r * g0r + g0i * g0i + 1.0f), s0);
                s1 = fmaf(w16c, __logf(g1r * g1r + g1i * g1i + 1.0f), s1);
            }
        } else {
            const float b1f = (slot >= 7) ? 1.0f : 0.0f;
            const float m1f = (slot >= 8) ? 1.0f : 0.0f;
#pragma unroll
            for (int kr = 0; kr < 32; ++kr) {
                const float lp = __logf(cre[kr] * cre[kr] + cim[kr] * cim[kr] + 1.0f);
                float wgt;
                if (kr >= 8 && kr <= 24)      wgt = 2.0f;
                else if (kr == 7)             wgt = 1.0f + m1f;
                else if (kr == 25)            wgt = b1f + 1.0f;
                else                          wgt = b1f + m1f;
                if (kr & 1) s1 = fmaf(wgt, lp, s1);
                else        s0 = fmaf(wgt, lp, s0);
            }
        }
        float s = s0 + s1;

#pragma unroll
        for (int off = 8; off >= 1; off >>= 1) s += __shfl_xor(s, off, 16);
        if (slot == 0 && p < total) out[p] = s;
    }
}

// 8 blocks x 1024 threads; one device atomicMax per block (8 total)
__global__ __launch_bounds__(1024) void max_kernel(
        const float* __restrict__ sums, int n, unsigned* __restrict__ mx) {
    __shared__ float sm[16];
    float m = 0.0f;  // sums are >= 0
    for (int i = blockIdx.x * 1024 + threadIdx.x; i < n; i += gridDim.x * 1024)
        m = fmaxf(m, sums[i]);
#pragma unroll
    for (int off = 32; off >= 1; off >>= 1) m = fmaxf(m, __shfl_xor(m, off, 64));
    if ((threadIdx.x & 63) == 0) sm[threadIdx.x >> 6] = m;
    __syncthreads();
    if (threadIdx.x == 0) {
#pragma unroll
        for (int i = 1; i < 16; ++i) m = fmaxf(m, sm[i]);
        atomicMax(mx, __float_as_uint(m));
    }
}

__global__ __launch_bounds__(256) void norm_kernel(
        float* __restrict__ out, int n, const unsigned* __restrict__ mx) {
    const int i = blockIdx.x * 256 + threadIdx.x;
    if (i < n) out[i] = out[i] / __uint_as_float(mx[0]);
}

extern "C" void kernel_launch(void* const* d_in, const int* in_sizes, int n_in,
                              void* d_out, int out_size, void* d_ws, size_t ws_size,
                              hipStream_t stream) {
    const float* x = (const float*)d_in[0];
    const float* w = (const float*)d_in[1];
    float* out = (float*)d_out;

    const int HWi = in_sizes[0] / 3;
    const int H = (int)(sqrt((double)HWi) + 0.5);
    const int W = H;
    const long long HW = (long long)H * W;
    const int mat = (int)(sqrt((double)out_size) + 0.5);
    const int total = mat * mat;

    unsigned* maxbuf = (unsigned*)d_ws;
    float* gray = (float*)((char*)d_ws + 256);
    const size_t gray_bytes = (size_t)HW * 4;
    unsigned* spec = (unsigned*)((char*)d_ws + 256 + gray_bytes);
    const size_t spec_bytes = (size_t)H * mat * 16 * 4;

    hipMemsetAsync(maxbuf, 0, 4, stream);

    const bool shape_ok = ((mat & 1) == 0) && (W == (mat - 1) * SCALE + PSZ)
                          && (H == (mat - 1) * SCALE + PSZ) && ((W & 3) == 0);

    if (shape_ok && ws_size >= 256 + gray_bytes + spec_bytes) {
        const int n4 = (int)(HW / 4);
        hipLaunchKernelGGL(gray_kernel, dim3((n4 + 255) / 256), dim3(256), 0, stream,
                           x, w, gray, n4, HW);
        const int rowtasks = H * (mat >> 1);
        hipLaunchKernelGGL(rowfft_kernel, dim3((rowtasks + 255) / 256), dim3(256), 0, stream,
                           gray, spec, H, W, mat);
        hipLaunchKernelGGL(colfft_kernel, dim3((total + 7) / 8), dim3(128), 0, stream,
                           spec, out, mat, mat);
    } else if (ws_size >= 256 + gray_bytes && (W & 3) == 0) {
        const int n4 = (int)(HW / 4);
        hipLaunchKernelGGL(gray_kernel, dim3((n4 + 255) / 256), dim3(256), 0, stream,
                           x, w, gray, n4, HW);
        hipLaunchKernelGGL((hfdft_patch_kernel<true>), dim3((total + 7) / 8), dim3(128), 0, stream,
                           gray, w, out, H, W, mat, mat);
    } else {
        hipLaunchKernelGGL((hfdft_patch_kernel<false>), dim3((total + 7) / 8), dim3(128), 0, stream,
                           x, w, out, H, W, mat, mat);
    }
    hipLaunchKernelGGL(max_kernel, dim3(8), dim3(1024), 0, stream, out, total, maxbuf);
    hipLaunchKernelGGL(norm_kernel, dim3((total + 255) / 256), dim3(256), 0, stream,
                       out, total, maxbuf);
}

// Round 7
// 44.847 us; speedup vs baseline: 1.3010x; 1.3010x over previous
//
#include <hip/hip_runtime.h>
#include <math.h>

#define SCALE 8
#define PSZ 32

// ---- constant twiddles: W_32^k = cos(2pi k/32) - i sin(2pi k/32), k=0..15 ----
__device__ constexpr float C32[16] = {
     1.000000000000000f,  0.980785280403230f,  0.923879532511287f,  0.831469612302545f,
     0.707106781186548f,  0.555570233019602f,  0.382683432365090f,  0.195090322016128f,
     0.000000000000000f, -0.195090322016128f, -0.382683432365090f, -0.555570233019602f,
    -0.707106781186548f, -0.831469612302545f, -0.923879532511287f, -0.980785280403230f };
__device__ constexpr float S32[16] = {
     0.000000000000000f,  0.195090322016128f,  0.382683432365090f,  0.555570233019602f,
     0.707106781186548f,  0.831469612302545f,  0.923879532511287f,  0.980785280403230f,
     1.000000000000000f,  0.980785280403230f,  0.923879532511287f,  0.831469612302545f,
     0.707106781186548f,  0.555570233019602f,  0.382683432365090f,  0.195090322016128f };

__device__ __forceinline__ constexpr int brev5(int i) {
    return ((i & 1) << 4) | ((i & 2) << 2) | (i & 4) | ((i & 8) >> 2) | ((i & 16) >> 4);
}

// in-place 32-point radix-2 DIT FFT, fully unrolled (all indices compile-time)
__device__ __forceinline__ void fft32(float re[PSZ], float im[PSZ]) {
#pragma unroll
    for (int i = 0; i < 32; ++i) {
        const int j = brev5(i);
        if (j > i) {
            float t = re[i]; re[i] = re[j]; re[j] = t;
            t = im[i]; im[i] = im[j]; im[j] = t;
        }
    }
#pragma unroll
    for (int s = 1; s <= 5; ++s) {
        const int m = 1 << s;
        const int h = m >> 1;
        const int tstep = 32 >> s;
#pragma unroll
        for (int k = 0; k < 32; k += m) {
#pragma unroll
            for (int j = 0; j < h; ++j) {
                const float wr = C32[j * tstep];
                const float wi = -S32[j * tstep];
                const int a = k + j;
                const int b = k + j + h;
                const float tr = wr * re[b] - wi * im[b];
                const float ti = wr * im[b] + wi * re[b];
                re[b] = re[a] - tr; im[b] = im[a] - ti;
                re[a] = re[a] + tr; im[a] = im[a] + ti;
            }
        }
    }
}

// bf16x2 pack/unpack (round-half-up via +0x8000)
__device__ __forceinline__ unsigned pack_bf2(float hi, float lo) {
    const unsigned uh = __float_as_uint(hi) + 0x8000u;
    const unsigned ul = __float_as_uint(lo) + 0x8000u;
    return (uh & 0xFFFF0000u) | (ul >> 16);
}
__device__ __forceinline__ float bf_hi(unsigned u) { return __uint_as_float(u & 0xFFFF0000u); }
__device__ __forceinline__ float bf_lo(unsigned u) { return __uint_as_float(u << 16); }

// ---- gray precompute: g = w0*R + w1*G + w2*B, vectorized float4 ----
__global__ __launch_bounds__(256) void gray_kernel(
        const float* __restrict__ x, const float* __restrict__ w,
        float* __restrict__ g, int n4, long long HW) {
    const int i = blockIdx.x * 256 + threadIdx.x;
    if (i >= n4) return;
    const float w0 = w[0], w1 = w[1], w2 = w[2];
    const float4 a = reinterpret_cast<const float4*>(x)[i];
    const float4 b = reinterpret_cast<const float4*>(x + HW)[i];
    const float4 c = reinterpret_cast<const float4*>(x + 2 * HW)[i];
    float4 o;
    o.x = w0 * a.x + w1 * b.x + w2 * c.x;
    o.y = w0 * a.y + w1 * b.y + w2 * c.y;
    o.z = w0 * a.z + w1 * b.z + w2 * c.z;
    o.w = w0 * a.w + w1 * b.w + w2 * c.w;
    reinterpret_cast<float4*>(g)[i] = o;
}

// 128-thread block = 2 independent waves; each wave handles 4 patches in its
// own private LDS slab (no cross-wave sharing -> wave-local lgkmcnt fence
// instead of s_barrier). __launch_bounds__(128, 4): VGPR cap 128 so the
// in-register FFT state (re[32]+im[32] live) does NOT spill — R4/R5's
// VGPR_Count=56 meant the compiler targeted 8 waves/EU and spilled ~2/3 of
// all VALU issue into shuffle traffic.
// Row stage: lane (g=lane>>5, r=lane&31) packs row r of patches (2g, 2g+1) as
// a + i*b -> ONE complex FFT32 -> unpack the two real-row spectra (Hermitian:
// k=0..16; k=0 & 16 real, packed into slot 0). LDS bf16x2, stride 33
// (2-way bank aliasing only = free).
// Col stage: lane (pl=lane>>4, slot=lane&15): 15 complex column FFTs + 1
// packed real-pair FFT per patch; masked log-power with Hermitian mirror
// weights {0,1,2}; 16-lane shuffle reduce.
template <bool GRAY_PRE>
__global__ __launch_bounds__(128, 4) void hfdft_patch_kernel(
        const float* __restrict__ x, const float* __restrict__ w,
        float* __restrict__ out, int H, int W, int mat_h, int mat_w) {
    __shared__ unsigned cb[8 * 528];   // 2 waves * 4 patches * 528 u32

    const int tid = threadIdx.x;
    const int wid = tid >> 6;
    const int lane = tid & 63;
    const int P0 = blockIdx.x * 8 + wid * 4;
    const int total = mat_h * mat_w;
    const long long HW = (long long)H * W;
    unsigned* cbw = cb + wid * 4 * 528;   // this wave's private slab

    // ================= row stage =================
    {
        const int g = lane >> 5, r = lane & 31;
        int pA = P0 + 2 * g;
        if (pA > total - 1) pA = total - 1;
        int pB = pA + 1; if (pB > total - 1) pB = total - 1;
        const int phA = pA / mat_w, pwA = pA % mat_w;
        const int phB = pB / mat_w, pwB = pB % mat_w;
        const bool adj = (phA == phB) && (pwB == pwA + 1);

        float re[PSZ], im[PSZ];
        if (GRAY_PRE) {
            if (adj) {
                const int base = (phA * SCALE + r) * W + pwA * SCALE;
                const float4* g4 = reinterpret_cast<const float4*>(x + base);
                float win[40];
#pragma unroll
                for (int q = 0; q < 10; ++q) {
                    const float4 v = g4[q];
                    win[4 * q + 0] = v.x; win[4 * q + 1] = v.y;
                    win[4 * q + 2] = v.z; win[4 * q + 3] = v.w;
                }
#pragma unroll
                for (int i = 0; i < PSZ; ++i) { re[i] = win[i]; im[i] = win[i + 8]; }
            } else {
                const int baseA = (phA * SCALE + r) * W + pwA * SCALE;
                const int baseB = (phB * SCALE + r) * W + pwB * SCALE;
#pragma unroll
                for (int i = 0; i < PSZ; ++i) { re[i] = x[baseA + i]; im[i] = x[baseB + i]; }
            }
        } else {
            const float w0 = w[0], w1 = w[1], w2 = w[2];
            if (adj && ((W & 3) == 0)) {
                const int base = (phA * SCALE + r) * W + pwA * SCALE;
                const float4* a4 = reinterpret_cast<const float4*>(x + base);
                const float4* b4 = reinterpret_cast<const float4*>(x + HW + base);
                const float4* c4 = reinterpret_cast<const float4*>(x + 2 * HW + base);
                float win[40];
#pragma unroll
                for (int q = 0; q < 10; ++q) {
                    const float4 a = a4[q], b = b4[q], c = c4[q];
                    win[4 * q + 0] = w0 * a.x + w1 * b.x + w2 * c.x;
                    win[4 * q + 1] = w0 * a.y + w1 * b.y + w2 * c.y;
                    win[4 * q + 2] = w0 * a.z + w1 * b.z + w2 * c.z;
                    win[4 * q + 3] = w0 * a.w + w1 * b.w + w2 * c.w;
                }
#pragma unroll
                for (int i = 0; i < PSZ; ++i) { re[i] = win[i]; im[i] = win[i + 8]; }
            } else {
                const int baseA = (phA * SCALE + r) * W + pwA * SCALE;
                const int baseB = (phB * SCALE + r) * W + pwB * SCALE;
#pragma unroll
                for (int i = 0; i < PSZ; ++i) {
                    re[i] = w0 * x[baseA + i] + w1 * x[HW + baseA + i] + w2 * x[2 * HW + baseA + i];
                    im[i] = w0 * x[baseB + i] + w1 * x[HW + baseB + i] + w2 * x[2 * HW + baseB + i];
                }
            }
        }

        fft32(re, im);   // FFT of rowA + i*rowB

        unsigned* cbA = cbw + (2 * g) * 528;
        unsigned* cbB = cbA + 528;
        cbA[r] = pack_bf2(re[0], re[16]);
        cbB[r] = pack_bf2(im[0], im[16]);
#pragma unroll
        for (int k = 1; k <= 15; ++k) {
            const int m = 32 - k;
            const float far_ = 0.5f * (re[k] + re[m]);
            const float fai_ = 0.5f * (im[k] - im[m]);
            const float fbr_ = 0.5f * (im[k] + im[m]);
            const float fbi_ = 0.5f * (re[m] - re[k]);
            cbA[k * 33 + r] = pack_bf2(far_, fai_);
            cbB[k * 33 + r] = pack_bf2(fbr_, fbi_);
        }
    }

    // waves don't share LDS: wave-local fence orders this wave's ds_writes
    // before its ds_reads (no s_barrier -> waves stay decoupled)
    asm volatile("s_waitcnt lgkmcnt(0)" ::: "memory");

    // ================= column stage =================
    {
        const int pl = lane >> 4, slot = lane & 15;
        const int p = P0 + pl;
        const unsigned* cbp = cbw + pl * 528 + slot * 33;

        float cre[PSZ], cim[PSZ];
#pragma unroll
        for (int r2 = 0; r2 < PSZ; ++r2) {
            const unsigned u = cbp[r2];
            cre[r2] = bf_hi(u);
            cim[r2] = bf_lo(u);
        }

        fft32(cre, cim);

        float s0 = 0.0f, s1 = 0.0f;
        if (slot == 0) {
            // packed pair (col 0, col 16): unpack kr=0..16, Hermitian-in-kr weights
#pragma unroll
            for (int kr = 0; kr <= 16; ++kr) {
                const int m = (32 - kr) & 31;
                const float g0r = 0.5f * (cre[kr] + cre[m]);
                const float g0i = 0.5f * (cim[kr] - cim[m]);
                const float g1r = 0.5f * (cim[kr] + cim[m]);
                const float g1i = 0.5f * (cre[m] - cre[kr]);
                const float w0c = (kr >= 7 ? 1.0f : 0.0f) + ((kr >= 8 && kr <= 15) ? 1.0f : 0.0f);
                const float w16c = 1.0f + ((kr >= 1 && kr <= 15) ? 1.0f : 0.0f);
                if (w0c > 0.0f)
                    s0 = fmaf(w0c, __logf(g0r * g0r + g0i * g0i + 1.0f), s0);
                s1 = fmaf(w16c, __logf(g1r * g1r + g1i * g1i + 1.0f), s1);
            }
        } else {
            const float b1f = (slot >= 7) ? 1.0f : 0.0f;
            const float m1f = (slot >= 8) ? 1.0f : 0.0f;
#pragma unroll
            for (int kr = 0; kr < 32; ++kr) {
                const float lp = __logf(cre[kr] * cre[kr] + cim[kr] * cim[kr] + 1.0f);
                float wgt;
                if (kr >= 8 && kr <= 24)      wgt = 2.0f;
                else if (kr == 7)             wgt = 1.0f + m1f;
                else if (kr == 25)            wgt = b1f + 1.0f;
                else                          wgt = b1f + m1f;
                if (kr & 1) s1 = fmaf(wgt, lp, s1);
                else        s0 = fmaf(wgt, lp, s0);
            }
        }
        float s = s0 + s1;

#pragma unroll
        for (int off = 8; off >= 1; off >>= 1) s += __shfl_xor(s, off, 16);
        if (slot == 0 && p < total) out[p] = s;
    }
}

// 8 blocks x 1024 threads; block b writes its partial max to partial[b]
// (plain store — no atomics, no memset needed)
__global__ __launch_bounds__(1024) void max_kernel(
        const float* __restrict__ sums, int n, float* __restrict__ partial) {
    __shared__ float sm[16];
    float m = 0.0f;  // sums are >= 0
    for (int i = blockIdx.x * 1024 + threadIdx.x; i < n; i += gridDim.x * 1024)
        m = fmaxf(m, sums[i]);
#pragma unroll
    for (int off = 32; off >= 1; off >>= 1) m = fmaxf(m, __shfl_xor(m, off, 64));
    if ((threadIdx.x & 63) == 0) sm[threadIdx.x >> 6] = m;
    __syncthreads();
    if (threadIdx.x == 0) {
#pragma unroll
        for (int i = 1; i < 16; ++i) m = fmaxf(m, sm[i]);
        partial[blockIdx.x] = m;
    }
}

__global__ __launch_bounds__(256) void norm_kernel(
        float* __restrict__ out, int n, const float* __restrict__ partial) {
    const int i = blockIdx.x * 256 + threadIdx.x;
    float m = partial[0];
#pragma unroll
    for (int b = 1; b < 8; ++b) m = fmaxf(m, partial[b]);
    if (i < n) out[i] = out[i] / m;
}

extern "C" void kernel_launch(void* const* d_in, const int* in_sizes, int n_in,
                              void* d_out, int out_size, void* d_ws, size_t ws_size,
                              hipStream_t stream) {
    const float* x = (const float*)d_in[0];
    const float* w = (const float*)d_in[1];
    float* out = (float*)d_out;

    const int HWi = in_sizes[0] / 3;
    const int H = (int)(sqrt((double)HWi) + 0.5);
    const int W = H;
    const long long HW = (long long)H * W;
    const int mat = (int)(sqrt((double)out_size) + 0.5);
    const int total = mat * mat;
    const int blocksA = (total + 7) / 8;

    float* partial = (float*)d_ws;                  // 8 floats
    float* gray = (float*)((char*)d_ws + 256);
    const size_t need = 256 + (size_t)HW * 4;

    if (ws_size >= need && (W & 3) == 0) {
        const int n4 = (int)(HW / 4);
        hipLaunchKernelGGL(gray_kernel, dim3((n4 + 255) / 256), dim3(256), 0, stream,
                           x, w, gray, n4, HW);
        hipLaunchKernelGGL((hfdft_patch_kernel<true>), dim3(blocksA), dim3(128), 0, stream,
                           gray, w, out, H, W, mat, mat);
    } else {
        hipLaunchKernelGGL((hfdft_patch_kernel<false>), dim3(blocksA), dim3(128), 0, stream,
                           x, w, out, H, W, mat, mat);
    }
    hipLaunchKernelGGL(max_kernel, dim3(8), dim3(1024), 0, stream, out, total, partial);
    hipLaunchKernelGGL(norm_kernel, dim3((total + 255) / 256), dim3(256), 0, stream,
                       out, total, partial);
}

// Round 8
// 42.405 us; speedup vs baseline: 1.3759x; 1.0576x over previous
//
#include <hip/hip_runtime.h>
#include <math.h>

#define SCALE 8
#define PSZ 32

// ---- constant twiddles: W_32^k = cos(2pi k/32) - i sin(2pi k/32), k=0..15 ----
__device__ constexpr float C32[16] = {
     1.000000000000000f,  0.980785280403230f,  0.923879532511287f,  0.831469612302545f,
     0.707106781186548f,  0.555570233019602f,  0.382683432365090f,  0.195090322016128f,
     0.000000000000000f, -0.195090322016128f, -0.382683432365090f, -0.555570233019602f,
    -0.707106781186548f, -0.831469612302545f, -0.923879532511287f, -0.980785280403230f };
__device__ constexpr float S32[16] = {
     0.000000000000000f,  0.195090322016128f,  0.382683432365090f,  0.555570233019602f,
     0.707106781186548f,  0.831469612302545f,  0.923879532511287f,  0.980785280403230f,
     1.000000000000000f,  0.980785280403230f,  0.923879532511287f,  0.831469612302545f,
     0.707106781186548f,  0.555570233019602f,  0.382683432365090f,  0.195090322016128f };

__device__ __forceinline__ constexpr int brev5(int i) {
    return ((i & 1) << 4) | ((i & 2) << 2) | (i & 4) | ((i & 8) >> 2) | ((i & 16) >> 4);
}

// in-place 32-point radix-2 DIT FFT, fully unrolled (all indices compile-time)
__device__ __forceinline__ void fft32(float re[PSZ], float im[PSZ]) {
#pragma unroll
    for (int i = 0; i < 32; ++i) {
        const int j = brev5(i);
        if (j > i) {
            float t = re[i]; re[i] = re[j]; re[j] = t;
            t = im[i]; im[i] = im[j]; im[j] = t;
        }
    }
#pragma unroll
    for (int s = 1; s <= 5; ++s) {
        const int m = 1 << s;
        const int h = m >> 1;
        const int tstep = 32 >> s;
#pragma unroll
        for (int k = 0; k < 32; k += m) {
#pragma unroll
            for (int j = 0; j < h; ++j) {
                const float wr = C32[j * tstep];
                const float wi = -S32[j * tstep];
                const int a = k + j;
                const int b = k + j + h;
                const float tr = wr * re[b] - wi * im[b];
                const float ti = wr * im[b] + wi * re[b];
                re[b] = re[a] - tr; im[b] = im[a] - ti;
                re[a] = re[a] + tr; im[a] = im[a] + ti;
            }
        }
    }
}

// bf16x2 pack/unpack (round-half-up via +0x8000)
__device__ __forceinline__ unsigned pack_bf2(float hi, float lo) {
    const unsigned uh = __float_as_uint(hi) + 0x8000u;
    const unsigned ul = __float_as_uint(lo) + 0x8000u;
    return (uh & 0xFFFF0000u) | (ul >> 16);
}
__device__ __forceinline__ float bf_hi(unsigned u) { return __uint_as_float(u & 0xFFFF0000u); }
__device__ __forceinline__ float bf_lo(unsigned u) { return __uint_as_float(u << 16); }

// ---- gray precompute: g = w0*R + w1*G + w2*B, vectorized float4 ----
__global__ __launch_bounds__(256) void gray_kernel(
        const float* __restrict__ x, const float* __restrict__ w,
        float* __restrict__ g, int n4, long long HW) {
    const int i = blockIdx.x * 256 + threadIdx.x;
    if (i >= n4) return;
    const float w0 = w[0], w1 = w[1], w2 = w[2];
    const float4 a = reinterpret_cast<const float4*>(x)[i];
    const float4 b = reinterpret_cast<const float4*>(x + HW)[i];
    const float4 c = reinterpret_cast<const float4*>(x + 2 * HW)[i];
    float4 o;
    o.x = w0 * a.x + w1 * b.x + w2 * c.x;
    o.y = w0 * a.y + w1 * b.y + w2 * c.y;
    o.z = w0 * a.z + w1 * b.z + w2 * c.z;
    o.w = w0 * a.w + w1 * b.w + w2 * c.w;
    reinterpret_cast<float4*>(g)[i] = o;
}

// 128-thread block = 2 independent waves; each wave handles 4 patches in its
// own private LDS slab (no cross-wave sharing -> wave-local lgkmcnt fence
// instead of s_barrier).
//
// REGISTER-PRESSURE NOTE (R7 post-mortem): the in-register FFT holds
// re[32]+im[32] live between every butterfly stage (>=64 floats), but the
// allocator kept squeezing to 56 VGPRs (R2..R7 all 56-60) and paying ~2.3x
// instruction inflation in AGPR-shuttle/remat. __launch_bounds__'s 2nd arg
// only sets the MIN waves/EU (a register CAP); the allocator still TARGETS
// max occupancy. amdgpu_waves_per_eu(2,4) sets max=4 waves/EU (which LDS
// already caps us at: 16.9KB/block -> ~4.5 waves/EU), telling the allocator
// there is no occupancy benefit below 128 VGPRs.
//
// Row stage: lane (g=lane>>5, r=lane&31) packs row r of patches (2g, 2g+1) as
// a + i*b -> ONE complex FFT32 -> unpack the two real-row spectra (Hermitian:
// k=0..16; k=0 & 16 real, packed into slot 0). LDS bf16x2, stride 33
// (2-way bank aliasing only = free).
// Col stage: lane (pl=lane>>4, slot=lane&15): 15 complex column FFTs + 1
// packed real-pair FFT per patch; masked log-power with Hermitian mirror
// weights {0,1,2}; 16-lane shuffle reduce.
template <bool GRAY_PRE>
__global__ __launch_bounds__(128)
__attribute__((amdgpu_waves_per_eu(2, 4)))
void hfdft_patch_kernel(
        const float* __restrict__ x, const float* __restrict__ w,
        float* __restrict__ out, int H, int W, int mat_h, int mat_w) {
    __shared__ unsigned cb[8 * 528];   // 2 waves * 4 patches * 528 u32

    const int tid = threadIdx.x;
    const int wid = tid >> 6;
    const int lane = tid & 63;
    const int P0 = blockIdx.x * 8 + wid * 4;
    const int total = mat_h * mat_w;
    const long long HW = (long long)H * W;
    unsigned* cbw = cb + wid * 4 * 528;   // this wave's private slab

    // ================= row stage =================
    {
        const int g = lane >> 5, r = lane & 31;
        int pA = P0 + 2 * g;
        if (pA > total - 1) pA = total - 1;
        int pB = pA + 1; if (pB > total - 1) pB = total - 1;
        const int phA = pA / mat_w, pwA = pA % mat_w;
        const int phB = pB / mat_w, pwB = pB % mat_w;
        const bool adj = (phA == phB) && (pwB == pwA + 1);

        float re[PSZ], im[PSZ];
        if (GRAY_PRE) {
            if (adj) {
                const int base = (phA * SCALE + r) * W + pwA * SCALE;
                const float4* g4 = reinterpret_cast<const float4*>(x + base);
                float win[40];
#pragma unroll
                for (int q = 0; q < 10; ++q) {
                    const float4 v = g4[q];
                    win[4 * q + 0] = v.x; win[4 * q + 1] = v.y;
                    win[4 * q + 2] = v.z; win[4 * q + 3] = v.w;
                }
#pragma unroll
                for (int i = 0; i < PSZ; ++i) { re[i] = win[i]; im[i] = win[i + 8]; }
            } else {
                const int baseA = (phA * SCALE + r) * W + pwA * SCALE;
                const int baseB = (phB * SCALE + r) * W + pwB * SCALE;
#pragma unroll
                for (int i = 0; i < PSZ; ++i) { re[i] = x[baseA + i]; im[i] = x[baseB + i]; }
            }
        } else {
            const float w0 = w[0], w1 = w[1], w2 = w[2];
            if (adj && ((W & 3) == 0)) {
                const int base = (phA * SCALE + r) * W + pwA * SCALE;
                const float4* a4 = reinterpret_cast<const float4*>(x + base);
                const float4* b4 = reinterpret_cast<const float4*>(x + HW + base);
                const float4* c4 = reinterpret_cast<const float4*>(x + 2 * HW + base);
                float win[40];
#pragma unroll
                for (int q = 0; q < 10; ++q) {
                    const float4 a = a4[q], b = b4[q], c = c4[q];
                    win[4 * q + 0] = w0 * a.x + w1 * b.x + w2 * c.x;
                    win[4 * q + 1] = w0 * a.y + w1 * b.y + w2 * c.y;
                    win[4 * q + 2] = w0 * a.z + w1 * b.z + w2 * c.z;
                    win[4 * q + 3] = w0 * a.w + w1 * b.w + w2 * c.w;
                }
#pragma unroll
                for (int i = 0; i < PSZ; ++i) { re[i] = win[i]; im[i] = win[i + 8]; }
            } else {
                const int baseA = (phA * SCALE + r) * W + pwA * SCALE;
                const int baseB = (phB * SCALE + r) * W + pwB * SCALE;
#pragma unroll
                for (int i = 0; i < PSZ; ++i) {
                    re[i] = w0 * x[baseA + i] + w1 * x[HW + baseA + i] + w2 * x[2 * HW + baseA + i];
                    im[i] = w0 * x[baseB + i] + w1 * x[HW + baseB + i] + w2 * x[2 * HW + baseB + i];
                }
            }
        }

        fft32(re, im);   // FFT of rowA + i*rowB

        unsigned* cbA = cbw + (2 * g) * 528;
        unsigned* cbB = cbA + 528;
        cbA[r] = pack_bf2(re[0], re[16]);
        cbB[r] = pack_bf2(im[0], im[16]);
#pragma unroll
        for (int k = 1; k <= 15; ++k) {
            const int m = 32 - k;
            const float far_ = 0.5f * (re[k] + re[m]);
            const float fai_ = 0.5f * (im[k] - im[m]);
            const float fbr_ = 0.5f * (im[k] + im[m]);
            const float fbi_ = 0.5f * (re[m] - re[k]);
            cbA[k * 33 + r] = pack_bf2(far_, fai_);
            cbB[k * 33 + r] = pack_bf2(fbr_, fbi_);
        }
    }

    // waves don't share LDS: wave-local fence orders this wave's ds_writes
    // before its ds_reads (no s_barrier -> waves stay decoupled)
    asm volatile("s_waitcnt lgkmcnt(0)" ::: "memory");

    // ================= column stage =================
    {
        const int pl = lane >> 4, slot = lane & 15;
        const int p = P0 + pl;
        const unsigned* cbp = cbw + pl * 528 + slot * 33;

        float cre[PSZ], cim[PSZ];
#pragma unroll
        for (int r2 = 0; r2 < PSZ; ++r2) {
            const unsigned u = cbp[r2];
            cre[r2] = bf_hi(u);
            cim[r2] = bf_lo(u);
        }

        fft32(cre, cim);

        float s0 = 0.0f, s1 = 0.0f;
        if (slot == 0) {
            // packed pair (col 0, col 16): unpack kr=0..16, Hermitian-in-kr weights
#pragma unroll
            for (int kr = 0; kr <= 16; ++kr) {
                const int m = (32 - kr) & 31;
                const float g0r = 0.5f * (cre[kr] + cre[m]);
                const float g0i = 0.5f * (cim[kr] - cim[m]);
                const float g1r = 0.5f * (cim[kr] + cim[m]);
                const float g1i = 0.5f * (cre[m] - cre[kr]);
                const float w0c = (kr >= 7 ? 1.0f : 0.0f) + ((kr >= 8 && kr <= 15) ? 1.0f : 0.0f);
                const float w16c = 1.0f + ((kr >= 1 && kr <= 15) ? 1.0f : 0.0f);
                if (w0c > 0.0f)
                    s0 = fmaf(w0c, __logf(g0r * g0r + g0i * g0i + 1.0f), s0);
                s1 = fmaf(w16c, __logf(g1r * g1r + g1i * g1i + 1.0f), s1);
            }
        } else {
            const float b1f = (slot >= 7) ? 1.0f : 0.0f;
            const float m1f = (slot >= 8) ? 1.0f : 0.0f;
#pragma unroll
            for (int kr = 0; kr < 32; ++kr) {
                const float lp = __logf(cre[kr] * cre[kr] + cim[kr] * cim[kr] + 1.0f);
                float wgt;
                if (kr >= 8 && kr <= 24)      wgt = 2.0f;
                else if (kr == 7)             wgt = 1.0f + m1f;
                else if (kr == 25)            wgt = b1f + 1.0f;
                else                          wgt = b1f + m1f;
                if (kr & 1) s1 = fmaf(wgt, lp, s1);
                else        s0 = fmaf(wgt, lp, s0);
            }
        }
        float s = s0 + s1;

#pragma unroll
        for (int off = 8; off >= 1; off >>= 1) s += __shfl_xor(s, off, 16);
        if (slot == 0 && p < total) out[p] = s;
    }
}

// 8 blocks x 1024 threads; block b writes its partial max to partial[b]
// (plain store — no atomics, no memset needed)
__global__ __launch_bounds__(1024) void max_kernel(
        const float* __restrict__ sums, int n, float* __restrict__ partial) {
    __shared__ float sm[16];
    float m = 0.0f;  // sums are >= 0
    for (int i = blockIdx.x * 1024 + threadIdx.x; i < n; i += gridDim.x * 1024)
        m = fmaxf(m, sums[i]);
#pragma unroll
    for (int off = 32; off >= 1; off >>= 1) m = fmaxf(m, __shfl_xor(m, off, 64));
    if ((threadIdx.x & 63) == 0) sm[threadIdx.x >> 6] = m;
    __syncthreads();
    if (threadIdx.x == 0) {
#pragma unroll
        for (int i = 1; i < 16; ++i) m = fmaxf(m, sm[i]);
        partial[blockIdx.x] = m;
    }
}

__global__ __launch_bounds__(256) void norm_kernel(
        float* __restrict__ out, int n, const float* __restrict__ partial) {
    const int i = blockIdx.x * 256 + threadIdx.x;
    float m = partial[0];
#pragma unroll
    for (int b = 1; b < 8; ++b) m = fmaxf(m, partial[b]);
    if (i < n) out[i] = out[i] / m;
}

extern "C" void kernel_launch(void* const* d_in, const int* in_sizes, int n_in,
                              void* d_out, int out_size, void* d_ws, size_t ws_size,
                              hipStream_t stream) {
    const float* x = (const float*)d_in[0];
    const float* w = (const float*)d_in[1];
    float* out = (float*)d_out;

    const int HWi = in_sizes[0] / 3;
    const int H = (int)(sqrt((double)HWi) + 0.5);
    const int W = H;
    const long long HW = (long long)H * W;
    const int mat = (int)(sqrt((double)out_size) + 0.5);
    const int total = mat * mat;
    const int blocksA = (total + 7) / 8;

    float* partial = (float*)d_ws;                  // 8 floats
    float* gray = (float*)((char*)d_ws + 256);
    const size_t need = 256 + (size_t)HW * 4;

    if (ws_size >= need && (W & 3) == 0) {
        const int n4 = (int)(HW / 4);
        hipLaunchKernelGGL(gray_kernel, dim3((n4 + 255) / 256), dim3(256), 0, stream,
                           x, w, gray, n4, HW);
        hipLaunchKernelGGL((hfdft_patch_kernel<true>), dim3(blocksA), dim3(128), 0, stream,
                           gray, w, out, H, W, mat, mat);
    } else {
        hipLaunchKernelGGL((hfdft_patch_kernel<false>), dim3(blocksA), dim3(128), 0, stream,
                           x, w, out, H, W, mat, mat);
    }
    hipLaunchKernelGGL(max_kernel, dim3(8), dim3(1024), 0, stream, out, total, partial);
    hipLaunchKernelGGL(norm_kernel, dim3((total + 255) / 256), dim3(256), 0, stream,
                       out, total, partial);
}